// Round 10
// baseline (36.886 us; speedup 1.0000x reference)
//
#include <hip/hip_runtime.h>
#include <hip/hip_bf16.h>
#include <math.h>

#define EMBED 128
#define VOCAB 32000
#define MEMN  50
#define BATCH 16
#define NQ    10
#define SQ    20
#define SS    40
#define BN    (BATCH*NQ)   // 160
#define NHOPS 3
#define NV    64           // vocab rows per k_out block

typedef short v8s __attribute__((ext_vector_type(8)));
typedef float v4f __attribute__((ext_vector_type(4)));

#define MFMA16 __builtin_amdgcn_mfma_f32_16x16x32_bf16

__device__ __forceinline__ float posw(int j, int J, int k) {
    float jf = (float)(j + 1) / (float)J;
    return 1.0f - jf - ((float)(k + 1) / (float)EMBED) * (1.0f - 2.0f * jf);
}

__device__ __forceinline__ short f2bf(float f) {
    __hip_bfloat16 h = __float2bfloat16(f);
    return *(short*)&h;
}
__device__ __forceinline__ float bf2f(short s) {
    __hip_bfloat16 h = *(__hip_bfloat16*)&s;
    return __bfloat162float(h);
}

// ---- Kernel 1: query embed [0,160) | story embed [160,960) | Hw hi/lo split [960,1088) ----
__global__ void k_embed(const int* __restrict__ cq, const int* __restrict__ story,
                        const float* __restrict__ Bw, const float* __restrict__ Aw,
                        const float* __restrict__ Cw, const float* __restrict__ TA,
                        const float* __restrict__ TC, const float* __restrict__ Hw,
                        float* __restrict__ state, float* __restrict__ memb,
                        float* __restrict__ outb, short* __restrict__ HwBhi,
                        short* __restrict__ HwBlo) {
    int blk = blockIdx.x;
    int t = threadIdx.x;   // 128
    if (blk < BN) {
        float acc = 0.f;
        #pragma unroll
        for (int s = 0; s < SQ; ++s) {
            int tok = cq[blk * SQ + s];
            acc += Bw[tok * EMBED + t] * posw(s, SQ, t);
        }
        state[blk * EMBED + t] = acc;
    } else if (blk < BN + BATCH * MEMN) {
        int br = blk - BN;
        int r = br % MEMN;
        float ma = TA[r * EMBED + t];
        float mc = TC[r * EMBED + t];
        const int* toks = story + br * SS;
        #pragma unroll 4
        for (int s = 0; s < SS; ++s) {
            int tok = toks[s];
            float w = posw(s, SS, t);
            ma += Aw[tok * EMBED + t] * w;
            mc += Cw[tok * EMBED + t] * w;
        }
        memb[br * EMBED + t] = ma;
        outb[br * EMBED + t] = mc;
    } else {
        int row = blk - (BN + BATCH * MEMN);   // 0..127
        float v = Hw[row * EMBED + t];
        short h = f2bf(v);
        HwBhi[row * EMBED + t] = h;
        HwBlo[row * EMBED + t] = f2bf(v - bf2f(h));
    }
}

// ---- Kernel 2 v4: per-batch MFMA hops. 16 blocks x 256 thr (4 waves).
// Split-bf16 (hi/lo) operands -> ~f32 precision; chunk-XOR swizzled LDS frags.
__global__ __launch_bounds__(256) void k_hops(const float* __restrict__ memb,
                                              const float* __restrict__ outb,
                                              const short* __restrict__ HwBhi,
                                              const short* __restrict__ HwBlo,
                                              const float* __restrict__ Hb,
                                              const float* __restrict__ state,
                                              __hip_bfloat16* __restrict__ stateb) {
    __shared__ short mem_hi[64][128], mem_lo[64][128];    // B for logits (rows>=50 zero)
    __shared__ short outT_hi[128][64], outT_lo[128][64];  // outb^T (cols>=50 zero)
    __shared__ short P_hi[16][64], P_lo[16][64];          // probs (rows>=10, cols>=50 zero)
    __shared__ short resp_hi[16][128], resp_lo[16][128];
    __shared__ float stateM[16][132];                     // +4 pad (f32 frag reads)
    __shared__ float Lg[16][64];
    __shared__ float Hb_l[128];

    int b = blockIdx.x;
    int t = threadIdx.x;    // 256
    int w = t >> 6;         // wave 0..3
    int l = t & 63;
    int c16 = l & 15;
    int kg = l >> 4;        // 0..3

    // ---- zero swizzle-scattered pads ----
    {
        v8s z = {0,0,0,0,0,0,0,0};
        for (int i = t; i < 64*128/8; i += 256) { ((v8s*)mem_hi)[i] = z; ((v8s*)mem_lo)[i] = z; }
        for (int i = t; i < 128*64/8; i += 256) { ((v8s*)outT_hi)[i] = z; ((v8s*)outT_lo)[i] = z; }
        for (int i = t; i < 16*64/8;  i += 256) { ((v8s*)P_hi)[i] = z; ((v8s*)P_lo)[i] = z; }
        for (int i = t; i < 16*132;   i += 256) ((float*)stateM)[i] = 0.f;
    }
    __syncthreads();

    // ---- stage: memb -> mem_hi/lo [r][k], outb -> outT_hi/lo [k][r], swizzled ----
    {
        const float4* mb4 = (const float4*)(memb + (size_t)b * MEMN * EMBED);
        const float4* ob4 = (const float4*)(outb + (size_t)b * MEMN * EMBED);
        for (int i = t; i < MEMN * EMBED / 4; i += 256) {   // 1600
            int r = i >> 5, c4 = (i & 31) << 2;
            float4 v = mb4[i];
            float4 u = ob4[i];
            float mv[4] = {v.x, v.y, v.z, v.w};
            float ov[4] = {u.x, u.y, u.z, u.w};
            #pragma unroll
            for (int j = 0; j < 4; ++j) {
                int k = c4 + j;
                short h = f2bf(mv[j]);
                int pos = (((k >> 3) ^ (r & 15)) << 3) | (k & 7);
                mem_hi[r][pos] = h;
                mem_lo[r][pos] = f2bf(mv[j] - bf2f(h));
                short g = f2bf(ov[j]);
                int posT = (((r >> 3) ^ (k & 7)) << 3) | (r & 7);
                outT_hi[k][posT] = g;
                outT_lo[k][posT] = f2bf(ov[j] - bf2f(g));
            }
        }
        for (int i = t; i < NQ * EMBED; i += 256) {
            int q = i >> 7, d = i & 127;
            stateM[q][d] = state[((size_t)b * NQ + q) * EMBED + d];
        }
        if (t < 128) Hb_l[t] = Hb[t];
    }
    __syncthreads();

    for (int hop = 0; hop < NHOPS; ++hop) {
        // ---- Phase L: Lg[q][r] = state . mem  (wave w -> r-cols w*16..+15) ----
        {
            v4f acc = {0.f, 0.f, 0.f, 0.f};
            int mrow = (w << 4) + c16;
            #pragma unroll
            for (int ks = 0; ks < 4; ++ks) {
                float4 s0 = *(const float4*)&stateM[c16][ks*32 + kg*8];
                float4 s1 = *(const float4*)&stateM[c16][ks*32 + kg*8 + 4];
                float sv[8] = {s0.x, s0.y, s0.z, s0.w, s1.x, s1.y, s1.z, s1.w};
                v8s ah, al;
                #pragma unroll
                for (int j = 0; j < 8; ++j) {
                    short h = f2bf(sv[j]);
                    ah[j] = h;
                    al[j] = f2bf(sv[j] - bf2f(h));
                }
                int pos = ((ks*4 + kg) ^ (mrow & 15)) << 3;
                v8s bh = *(const v8s*)&mem_hi[mrow][pos];
                v8s bl = *(const v8s*)&mem_lo[mrow][pos];
                acc = MFMA16(ah, bh, acc, 0, 0, 0);
                acc = MFMA16(al, bh, acc, 0, 0, 0);
                acc = MFMA16(ah, bl, acc, 0, 0, 0);
            }
            #pragma unroll
            for (int i = 0; i < 4; ++i) Lg[kg*4 + i][(w << 4) + c16] = acc[i];
        }
        __syncthreads();
        // ---- Phase SM: softmax per query row (wave w -> q = w, w+4, w+8) ----
        for (int q = w; q < NQ; q += 4) {
            float v = (l < MEMN) ? Lg[q][l] : -1e30f;
            float mx = v;
            #pragma unroll
            for (int off = 32; off; off >>= 1) mx = fmaxf(mx, __shfl_xor(mx, off, 64));
            float e = (l < MEMN) ? __expf(v - mx) : 0.f;
            float ss = e;
            #pragma unroll
            for (int off = 32; off; off >>= 1) ss += __shfl_xor(ss, off, 64);
            if (l < MEMN) {
                float p = e / ss;
                short h = f2bf(p);
                int pos = (((l >> 3) ^ (q & 7)) << 3) | (l & 7);
                P_hi[q][pos] = h;
                P_lo[q][pos] = f2bf(p - bf2f(h));
            }
        }
        __syncthreads();
        // ---- Phase PV: resp[q][d] = P . outb  (wave w -> d-tiles w*16, w*16+64) ----
        {
            v8s ph[2], pl[2];
            #pragma unroll
            for (int ks = 0; ks < 2; ++ks) {
                int pos = ((ks*4 + kg) ^ (c16 & 7)) << 3;
                ph[ks] = *(const v8s*)&P_hi[c16][pos];
                pl[ks] = *(const v8s*)&P_lo[c16][pos];
            }
            #pragma unroll
            for (int tile = 0; tile < 2; ++tile) {
                int d = (w << 4) + tile * 64;
                int orow = d + c16;
                v4f acc = {0.f, 0.f, 0.f, 0.f};
                #pragma unroll
                for (int ks = 0; ks < 2; ++ks) {
                    int pos = ((ks*4 + kg) ^ (orow & 7)) << 3;
                    v8s bh = *(const v8s*)&outT_hi[orow][pos];
                    v8s bl = *(const v8s*)&outT_lo[orow][pos];
                    acc = MFMA16(ph[ks], bh, acc, 0, 0, 0);
                    acc = MFMA16(pl[ks], bh, acc, 0, 0, 0);
                    acc = MFMA16(ph[ks], bl, acc, 0, 0, 0);
                }
                #pragma unroll
                for (int i = 0; i < 4; ++i) {
                    int row = kg*4 + i, col = d + c16;
                    float v = acc[i];
                    short h = f2bf(v);
                    int pos = (((col >> 3) ^ (row & 15)) << 3) | (col & 7);
                    resp_hi[row][pos] = h;
                    resp_lo[row][pos] = f2bf(v - bf2f(h));
                }
            }
        }
        __syncthreads();
        // ---- Phase H: state'[q][d] = resp @ Hw^T + Hb + state ----
        {
            v8s rh[4], rl[4];
            #pragma unroll
            for (int ks = 0; ks < 4; ++ks) {
                int pos = ((ks*4 + kg) ^ (c16 & 15)) << 3;
                rh[ks] = *(const v8s*)&resp_hi[c16][pos];
                rl[ks] = *(const v8s*)&resp_lo[c16][pos];
            }
            #pragma unroll
            for (int tile = 0; tile < 2; ++tile) {
                int d = (w << 4) + tile * 64;
                int hrow = d + c16;
                const v8s* gh = (const v8s*)(HwBhi + (size_t)hrow * EMBED);
                const v8s* gl = (const v8s*)(HwBlo + (size_t)hrow * EMBED);
                v4f acc = {0.f, 0.f, 0.f, 0.f};
                #pragma unroll
                for (int ks = 0; ks < 4; ++ks) {
                    v8s bh = gh[ks*4 + kg];
                    v8s bl = gl[ks*4 + kg];
                    acc = MFMA16(rh[ks], bh, acc, 0, 0, 0);
                    acc = MFMA16(rl[ks], bh, acc, 0, 0, 0);
                    acc = MFMA16(rh[ks], bl, acc, 0, 0, 0);
                }
                #pragma unroll
                for (int i = 0; i < 4; ++i) {
                    int row = kg*4 + i, col = d + c16;
                    stateM[row][col] = acc[i] + Hb_l[col] + stateM[row][col];
                }
            }
        }
        __syncthreads();
    }
    // ---- emit bf16 state for k_out ----
    for (int i = t; i < NQ * EMBED; i += 256) {
        int q = i >> 7, d = i & 127;
        stateb[((size_t)b * NQ + q) * EMBED + d] = __float2bfloat16(stateM[q][d]);
    }
}

// ---- Kernel 3 (R8-exact): MFMA GEMM out[160,32000] ----
__global__ __launch_bounds__(256) void k_out(const __hip_bfloat16* __restrict__ stateb,
                                             const float* __restrict__ outw,
                                             float* __restrict__ out) {
    __shared__ __align__(16) __hip_bfloat16 Alds[BN][EMBED + 8];
    __shared__ __align__(16) __hip_bfloat16 Blds[NV][EMBED + 8];
    int t = threadIdx.x;
    int vbase = blockIdx.x * NV;

    #pragma unroll
    for (int i = 0; i < 10; ++i) {
        int e = t + i * 256;
        int row = e >> 4, c8 = (e & 15) << 3;
        *(int4*)&Alds[row][c8] = *(const int4*)&stateb[row * EMBED + c8];
    }
    #pragma unroll
    for (int i = 0; i < 8; ++i) {
        int e = t + i * 256;
        int row = e >> 5, c4 = (e & 31) << 2;
        float4 w = *(const float4*)&outw[(size_t)(vbase + row) * EMBED + c4];
        short4 p;
        p.x = f2bf(w.x); p.y = f2bf(w.y); p.z = f2bf(w.z); p.w = f2bf(w.w);
        *(short4*)&Blds[row][c4] = p;
    }
    __syncthreads();

    int wv = t >> 6;
    int l = t & 63;
    int col16 = l & 15;
    int kg = l >> 4;

    v8s bfrag[4];
    #pragma unroll
    for (int k4 = 0; k4 < 4; ++k4)
        bfrag[k4] = *(v8s*)&Blds[(wv << 4) + col16][k4 * 32 + kg * 8];

    v4f acc[10];
    #pragma unroll
    for (int m = 0; m < 10; ++m) acc[m] = (v4f){0.f, 0.f, 0.f, 0.f};

    #pragma unroll
    for (int k4 = 0; k4 < 4; ++k4) {
        #pragma unroll
        for (int m = 0; m < 10; ++m) {
            v8s af = *(v8s*)&Alds[m * 16 + col16][k4 * 32 + kg * 8];
            acc[m] = MFMA16(af, bfrag[k4], acc[m], 0, 0, 0);
        }
    }

    int colg = vbase + (wv << 4) + col16;
    #pragma unroll
    for (int m = 0; m < 10; ++m) {
        #pragma unroll
        for (int i = 0; i < 4; ++i) {
            out[(size_t)(m * 16 + kg * 4 + i) * VOCAB + colg] = acc[m][i];
        }
    }
}

extern "C" void kernel_launch(void* const* d_in, const int* in_sizes, int n_in,
                              void* d_out, int out_size, void* d_ws, size_t ws_size,
                              hipStream_t stream) {
    const int*   ctx_query = (const int*)  d_in[0];
    const int*   story     = (const int*)  d_in[1];
    const float* A_w       = (const float*)d_in[2];
    const float* C_w       = (const float*)d_in[3];
    const float* B_w       = (const float*)d_in[4];
    const float* H_w       = (const float*)d_in[5];
    const float* H_b       = (const float*)d_in[6];
    const float* out_w     = (const float*)d_in[7];
    const float* TA        = (const float*)d_in[8];
    const float* TC        = (const float*)d_in[9];
    float* out = (float*)d_out;

    float* ws    = (float*)d_ws;
    float* state = ws;                                   // 160*128 f32
    float* memb  = state + BN * EMBED;                   // 800*128 f32
    float* outb  = memb + BATCH * MEMN * EMBED;          // 800*128 f32
    short* HwBhi = (short*)(outb + BATCH * MEMN * EMBED);// 128*128 bf16
    short* HwBlo = HwBhi + EMBED * EMBED;                // 128*128 bf16
    __hip_bfloat16* stateb = (__hip_bfloat16*)(HwBlo + EMBED * EMBED);  // 160*128 bf16

    k_embed<<<BN + BATCH * MEMN + EMBED, 128, 0, stream>>>(
        ctx_query, story, B_w, A_w, C_w, TA, TC, H_w, state, memb, outb, HwBhi, HwBlo);
    k_hops<<<BATCH, 256, 0, stream>>>(memb, outb, HwBhi, HwBlo, H_b, state, stateb);
    k_out<<<VOCAB / NV, 256, 0, stream>>>(stateb, out_w, out);
}